// Round 8
// baseline (69.702 us; speedup 1.0000x reference)
//
#include <hip/hip_runtime.h>
#include <math.h>

#define D 100
#define K 4
#define NREL 1000
#define CH 8
#define NT 512

// --- Grouping: one 1024-thread block. LDS histogram -> scan -> scatter.
// Emits start[NREL+1], bucket batch-index bb, and pre-gathered head/tail ids.
__global__ __launch_bounds__(1024) void k_group(
    const int* __restrict__ rels, const int* __restrict__ heads,
    const int* __restrict__ tails, int B,
    int* __restrict__ start, int* __restrict__ bb,
    int* __restrict__ bh, int* __restrict__ bt)
{
    __shared__ int sA[1024], sB[1024];
    const int tid = threadIdx.x;
    sA[tid] = 0;
    __syncthreads();
    for (int b = tid; b < B; b += 1024) atomicAdd(&sA[rels[b]], 1);
    __syncthreads();
    const int v = sA[tid];
    int* src = sA; int* dst = sB;
    for (int off = 1; off < 1024; off <<= 1) {
        int x = src[tid];
        if (tid >= off) x += src[tid - off];
        dst[tid] = x;
        __syncthreads();
        int* t = src; src = dst; dst = t;
    }
    const int excl = src[tid] - v;     // exclusive scan
    if (tid < NREL) start[tid] = excl;
    if (tid == 0)   start[NREL] = B;
    int* cur = dst;                    // free buffer -> cursors
    cur[tid] = excl;
    __syncthreads();
    for (int b = tid; b < B; b += 1024) {
        const int r = rels[b];
        const int pos = atomicAdd(&cur[r], 1);
        bb[pos] = b;
        bh[pos] = heads[b];
        bt[pos] = tails[b];
    }
}

// One block per relation: 8 waves = (slice k 0..3) x (item-half h 0..1).
// Each wave: 4 items in registers (e2r[4]), ALL 100 rows of its W slice,
// 5 independent float4 loads in flight. True VGPR need ~60 -> fits the 64
// cap at 100% occupancy, no spill. h=1 waves skip work when n<=4 (58% of
// relations) so W is then read once. Per-item arithmetic order fixed ->
// bitwise deterministic regardless of bucket scatter order.
#define WFMA(u) { const int rr = r0 + 2*(u); \
    acc0 += (wv##u.x*e20.x + wv##u.y*e20.y + wv##u.z*e20.z + wv##u.w*e20.w) * e1p[0*2*D + rr]; \
    acc1 += (wv##u.x*e21.x + wv##u.y*e21.y + wv##u.z*e21.z + wv##u.w*e21.w) * e1p[1*2*D + rr]; \
    acc2 += (wv##u.x*e22.x + wv##u.y*e22.y + wv##u.z*e22.z + wv##u.w*e22.w) * e1p[2*2*D + rr]; \
    acc3 += (wv##u.x*e23.x + wv##u.y*e23.y + wv##u.z*e23.z + wv##u.w*e23.w) * e1p[3*2*D + rr]; }

__global__ __launch_bounds__(NT, 8) void ntn_main(
    const float* __restrict__ E, const float* __restrict__ W,
    const float* __restrict__ V, const float* __restrict__ Bp,
    const float* __restrict__ U, const int* __restrict__ start,
    const int* __restrict__ bb, const int* __restrict__ bh,
    const int* __restrict__ bt, float* __restrict__ out)
{
    const int r  = blockIdx.x;
    const int cs = start[r];
    const int n  = start[r + 1] - cs;
    if (n <= 0) return;

    const int tid  = threadIdx.x;
    const int lane = tid & 63;
    const int w    = tid >> 6;       // 0..7
    const int k    = w & 3;          // tensor slice
    const int h    = w >> 2;         // item half: items [h*4, h*4+4)
    const int dsub = lane / 25;      // 0/1 for lanes < 50
    const int c    = lane % 25;      // float4 column group
    const bool active = (lane < 50);

    __shared__ float e12[CH][2 * D];
    __shared__ float red[8][4];
    __shared__ int   ob[CH];

    const float4* Wk4 = reinterpret_cast<const float4*>(W + ((size_t)r * K + k) * D * D);
    const float*  Vk  = V + ((size_t)r * K + k) * 2 * D;
    const float4* E4  = reinterpret_cast<const float4*>(E);

    for (int base = 0; base < n; base += CH) {
        const int m = min(CH, n - base);
        __syncthreads();   // previous chunk fully consumed before overwrite
        if (tid < m) ob[tid] = bb[cs + base + tid];
        // wave w gathers item w: head row -> e12[w][0:100), tail -> [100:200)
        if (active && w < m) {
            const int idx = cs + base + w;                 // wave-uniform
            const int ent = dsub ? bt[idx] : bh[idx];
            *(float4*)&e12[w][dsub * D + c * 4] = E4[(size_t)ent * 25 + c];
        }
        __syncthreads();

        float acc0 = 0.f, acc1 = 0.f, acc2 = 0.f, acc3 = 0.f;
        if (h * 4 < m) {   // this half has at least one valid item
            const float* e1p = &e12[h * 4][0];
            // e2 column-group for the 4 items -> 16 VGPRs (safe for all lanes)
            const float4 e20 = *(const float4*)&e12[h * 4 + 0][D + c * 4];
            const float4 e21 = *(const float4*)&e12[h * 4 + 1][D + c * 4];
            const float4 e22 = *(const float4*)&e12[h * 4 + 2][D + c * 4];
            const float4 e23 = *(const float4*)&e12[h * 4 + 3][D + c * 4];

            if (active) {
                #pragma unroll 1   // keep exactly 5 loads in flight (VGPR fit)
                for (int bat = 0; bat < 10; ++bat) {
                    const int r0 = bat * 10 + dsub;        // rows r0,r0+2,..,r0+8
                    const float4 wv0 = Wk4[(r0    ) * 25 + c];
                    const float4 wv1 = Wk4[(r0 + 2) * 25 + c];
                    const float4 wv2 = Wk4[(r0 + 4) * 25 + c];
                    const float4 wv3 = Wk4[(r0 + 6) * 25 + c];
                    const float4 wv4 = Wk4[(r0 + 8) * 25 + c];
                    WFMA(0) WFMA(1) WFMA(2) WFMA(3) WFMA(4)
                }
            }
            // g_a: v[r,k,:].[e1;e2] for this wave's own items (all 64 lanes)
            for (int j = lane; j < 2 * D; j += 64) {
                const float vv = Vk[j];
                acc0 += vv * e1p[0 * 2 * D + j];
                acc1 += vv * e1p[1 * 2 * D + j];
                acc2 += vv * e1p[2 * 2 * D + j];
                acc3 += vv * e1p[3 * 2 * D + j];
            }
        }
        #pragma unroll
        for (int off = 32; off > 0; off >>= 1) {
            acc0 += __shfl_down(acc0, off, 64);
            acc1 += __shfl_down(acc1, off, 64);
            acc2 += __shfl_down(acc2, off, 64);
            acc3 += __shfl_down(acc3, off, 64);
        }
        if (lane == 0) {
            red[w][0] = acc0; red[w][1] = acc1;
            red[w][2] = acc2; red[w][3] = acc3;
        }
        __syncthreads();
        if (tid < m) {   // fused epilogue; partial (item,k) = red[(it>>2)*4+k][it&3]
            const int rb = r * K;
            const int hr = (tid >> 2) * 4, il = tid & 3;
            float score = 0.f;
            #pragma unroll
            for (int kk = 0; kk < K; ++kk) {
                const float gv = red[hr + kk][il] + Bp[rb + kk];
                score += U[rb + kk] * tanhf(gv);
            }
            out[ob[tid]] = 1.f / (1.f + expf(-score));
        }
    }
}

extern "C" void kernel_launch(void* const* d_in, const int* in_sizes, int n_in,
                              void* d_out, int out_size, void* d_ws, size_t ws_size,
                              hipStream_t stream) {
    const int*   heads = (const int*)d_in[0];
    const int*   tails = (const int*)d_in[1];
    const int*   rels  = (const int*)d_in[2];
    const float* E     = (const float*)d_in[3];
    const float* W     = (const float*)d_in[4];
    const float* V     = (const float*)d_in[5];
    const float* Bp    = (const float*)d_in[6];
    const float* U     = (const float*)d_in[7];
    float* out = (float*)d_out;

    const int B = in_sizes[0];
    int* start = (int*)d_ws;           // [NREL+1]
    int* bb    = start + 1024;         // [B]
    int* bh    = bb + B;               // [B]
    int* bt    = bh + B;               // [B]

    k_group<<<1, 1024, 0, stream>>>(rels, heads, tails, B, start, bb, bh, bt);
    ntn_main<<<NREL, NT, 0, stream>>>(E, W, V, Bp, U, start, bb, bh, bt, out);
}

// Round 9
// 58.232 us; speedup vs baseline: 1.1970x; 1.1970x over previous
//
#include <hip/hip_runtime.h>
#include <math.h>

#define D 100
#define K 4
#define NREL 1000
#define CH 8
#define NT 512

// --- Grouping: one 1024-thread block. LDS histogram -> scan -> scatter.
// Emits start[NREL+1], bucket batch-index bb, and pre-gathered head/tail ids.
__global__ __launch_bounds__(1024) void k_group(
    const int* __restrict__ rels, const int* __restrict__ heads,
    const int* __restrict__ tails, int B,
    int* __restrict__ start, int* __restrict__ bb,
    int* __restrict__ bh, int* __restrict__ bt)
{
    __shared__ int sA[1024], sB[1024];
    const int tid = threadIdx.x;
    sA[tid] = 0;
    __syncthreads();
    for (int b = tid; b < B; b += 1024) atomicAdd(&sA[rels[b]], 1);
    __syncthreads();
    const int v = sA[tid];
    int* src = sA; int* dst = sB;
    for (int off = 1; off < 1024; off <<= 1) {
        int x = src[tid];
        if (tid >= off) x += src[tid - off];
        dst[tid] = x;
        __syncthreads();
        int* t = src; src = dst; dst = t;
    }
    const int excl = src[tid] - v;     // exclusive scan
    if (tid < NREL) start[tid] = excl;
    if (tid == 0)   start[NREL] = B;
    int* cur = dst;                    // free buffer -> cursors
    cur[tid] = excl;
    __syncthreads();
    for (int b = tid; b < B; b += 1024) {
        const int r = rels[b];
        const int pos = atomicAdd(&cur[r], 1);
        bb[pos] = b;
        bh[pos] = heads[b];
        bt[pos] = tails[b];
    }
}

// One block per relation: 8 waves = (slice k 0..3) x (item-half h 0..1).
// Each wave: 4 items, ALL 100 rows of its W slice, SIMPLE inner loop
// (unroll 4, no hand-built pipeline) under a roomy 128-VGPR cap -> the
// compiler schedules loads ahead without spilling (R6-R8 post-mortem).
// Per-item arithmetic order fixed -> bitwise deterministic regardless of
// bucket scatter order.
__global__ __launch_bounds__(NT, 4) void ntn_main(
    const float* __restrict__ E, const float* __restrict__ W,
    const float* __restrict__ V, const float* __restrict__ Bp,
    const float* __restrict__ U, const int* __restrict__ start,
    const int* __restrict__ bb, const int* __restrict__ bh,
    const int* __restrict__ bt, float* __restrict__ out)
{
    const int r  = blockIdx.x;
    const int cs = start[r];
    const int n  = start[r + 1] - cs;
    if (n <= 0) return;

    const int tid  = threadIdx.x;
    const int lane = tid & 63;
    const int w    = tid >> 6;       // 0..7
    const int k    = w & 3;          // tensor slice
    const int h    = w >> 2;         // item half: items [h*4, h*4+4)
    const int dsub = lane / 25;      // 0/1 for lanes < 50
    const int c    = lane % 25;      // float4 column group
    const bool active = (lane < 50);

    __shared__ float e12[CH][2 * D];
    __shared__ float red[8][4];
    __shared__ int   ob[CH];

    const float4* Wk4 = reinterpret_cast<const float4*>(W + ((size_t)r * K + k) * D * D);
    const float*  Vk  = V + ((size_t)r * K + k) * 2 * D;
    const float4* E4  = reinterpret_cast<const float4*>(E);

    for (int base = 0; base < n; base += CH) {
        const int m = min(CH, n - base);
        __syncthreads();   // previous chunk fully consumed before overwrite
        if (tid < m) ob[tid] = bb[cs + base + tid];
        // wave w gathers item w: head row -> e12[w][0:100), tail -> [100:200)
        if (active && w < m) {
            const int idx = cs + base + w;                 // wave-uniform
            const int ent = dsub ? bt[idx] : bh[idx];
            *(float4*)&e12[w][dsub * D + c * 4] = E4[(size_t)ent * 25 + c];
        }
        __syncthreads();

        float acc0 = 0.f, acc1 = 0.f, acc2 = 0.f, acc3 = 0.f;
        if (h * 4 < m) {   // this half has at least one valid item
            const float* e1p0 = &e12[h * 4 + 0][0];
            const float* e1p1 = &e12[h * 4 + 1][0];
            const float* e1p2 = &e12[h * 4 + 2][0];
            const float* e1p3 = &e12[h * 4 + 3][0];
            // e2 column-group for the 4 items (16 VGPR, fixed per lane)
            const float4 e20 = *(const float4*)&e12[h * 4 + 0][D + c * 4];
            const float4 e21 = *(const float4*)&e12[h * 4 + 1][D + c * 4];
            const float4 e22 = *(const float4*)&e12[h * 4 + 2][D + c * 4];
            const float4 e23 = *(const float4*)&e12[h * 4 + 3][D + c * 4];

            if (active) {
                #pragma unroll 4
                for (int rr = 0; rr < 50; ++rr) {
                    const int d = rr * 2 + dsub;
                    const float4 wv = Wk4[d * 25 + c];
                    acc0 += (wv.x * e20.x + wv.y * e20.y + wv.z * e20.z + wv.w * e20.w) * e1p0[d];
                    acc1 += (wv.x * e21.x + wv.y * e21.y + wv.z * e21.z + wv.w * e21.w) * e1p1[d];
                    acc2 += (wv.x * e22.x + wv.y * e22.y + wv.z * e22.z + wv.w * e22.w) * e1p2[d];
                    acc3 += (wv.x * e23.x + wv.y * e23.y + wv.z * e23.z + wv.w * e23.w) * e1p3[d];
                }
            }
            // g_a: v[r,k,:].[e1;e2] for this wave's own items (all 64 lanes)
            for (int j = lane; j < 2 * D; j += 64) {
                const float vv = Vk[j];
                acc0 += vv * e1p0[j];
                acc1 += vv * e1p1[j];
                acc2 += vv * e1p2[j];
                acc3 += vv * e1p3[j];
            }
        }
        #pragma unroll
        for (int off = 32; off > 0; off >>= 1) {
            acc0 += __shfl_down(acc0, off, 64);
            acc1 += __shfl_down(acc1, off, 64);
            acc2 += __shfl_down(acc2, off, 64);
            acc3 += __shfl_down(acc3, off, 64);
        }
        if (lane == 0) {
            red[w][0] = acc0; red[w][1] = acc1;
            red[w][2] = acc2; red[w][3] = acc3;
        }
        __syncthreads();
        if (tid < m) {   // fused epilogue; partial (item,k) = red[(it>>2)*4+k][it&3]
            const int rb = r * K;
            const int hr = (tid >> 2) * 4, il = tid & 3;
            float score = 0.f;
            #pragma unroll
            for (int kk = 0; kk < K; ++kk) {
                const float gv = red[hr + kk][il] + Bp[rb + kk];
                score += U[rb + kk] * tanhf(gv);
            }
            out[ob[tid]] = 1.f / (1.f + expf(-score));
        }
    }
}

extern "C" void kernel_launch(void* const* d_in, const int* in_sizes, int n_in,
                              void* d_out, int out_size, void* d_ws, size_t ws_size,
                              hipStream_t stream) {
    const int*   heads = (const int*)d_in[0];
    const int*   tails = (const int*)d_in[1];
    const int*   rels  = (const int*)d_in[2];
    const float* E     = (const float*)d_in[3];
    const float* W     = (const float*)d_in[4];
    const float* V     = (const float*)d_in[5];
    const float* Bp    = (const float*)d_in[6];
    const float* U     = (const float*)d_in[7];
    float* out = (float*)d_out;

    const int B = in_sizes[0];
    int* start = (int*)d_ws;           // [NREL+1]
    int* bb    = start + 1024;         // [B]
    int* bh    = bb + B;               // [B]
    int* bt    = bh + B;               // [B]

    k_group<<<1, 1024, 0, stream>>>(rels, heads, tails, B, start, bb, bh, bt);
    ntn_main<<<NREL, NT, 0, stream>>>(E, W, V, Bp, U, start, bb, bh, bt, out);
}